// Round 8
// baseline (420.065 us; speedup 1.0000x reference)
//
#include <hip/hip_runtime.h>
#include <hip/hip_bf16.h>
#include <stdint.h>

// B=4, S=2048, D=1024, H=16, Hd=64
#define SEQ 2048
#define DIM 1024
#define NH 16
#define HD 64

typedef __attribute__((ext_vector_type(8))) short short8;
typedef __attribute__((ext_vector_type(4))) float f32x4;
typedef __attribute__((ext_vector_type(4))) float float4v;
typedef __attribute__((ext_vector_type(4))) unsigned short u16x4;
typedef __attribute__((ext_vector_type(2))) unsigned int u32x2;

#define MFMA16(a, b, c) __builtin_amdgcn_mfma_f32_16x16x32_bf16(a, b, c, 0, 0, 0)

// 0.125 * log2(e): folds both the 1/sqrt(Hd) scale and the exp->exp2 base
// change into the Q projection, so attention softmax uses exp2 directly.
#define QSCALE 0.1803368801111244f
#define LOG2_THR 11.0f  // defer-max threshold (log2 domain), P <= 2^11

__device__ __forceinline__ unsigned short f2b(float f) {
  union { float f; unsigned int u; } x; x.f = f;
  unsigned int r = (x.u + 0x7FFFu + ((x.u >> 16) & 1u)) >> 16;
  return (unsigned short)r;
}

// native exp2: v_exp_f32 (ISA section 3: D = 2^S0). exp2f() is the OCML
// precise libm path (~10+ VALU each) -- that was the round-3/4 VALU bloat.
__device__ __forceinline__ float exp2v(float x) {
  float r;
  asm("v_exp_f32 %0, %1" : "=v"(r) : "v"(x));
  return r;
}

// pack two f32 -> one u32 of 2xbf16 (low = a, high = b), round-nearest
__device__ __forceinline__ unsigned int pk2(float a, float b) {
  __hip_bfloat162 h = __float22bfloat162_rn(float2{a, b});
  union { __hip_bfloat162 h; unsigned int u; } c; c.h = h;
  return c.u;
}

// global -> LDS async copy, 16B per lane. LDS dest must be linear (base + lane*16).
__device__ __forceinline__ void gld16(const void* g, void* l) {
  __builtin_amdgcn_global_load_lds(
      (const __attribute__((address_space(1))) unsigned int*)(uintptr_t)g,
      (__attribute__((address_space(3))) unsigned int*)(unsigned int)(uintptr_t)l,
      16, 0, 0);
}

// ---------------- prep: fp32 -> bf16 cast (vectorized) ----------------
__global__ void cast_bf16_kernel(const float* __restrict__ in,
                                 unsigned short* __restrict__ out, int n4) {
  int stride = gridDim.x * blockDim.x;
  for (int i = blockIdx.x * blockDim.x + threadIdx.x; i < n4; i += stride) {
    float4v v = *(const float4v*)(in + (size_t)i * 4);
    u16x4 o;
    o.x = f2b(v.x); o.y = f2b(v.y); o.z = f2b(v.z); o.w = f2b(v.w);
    *(u16x4*)(out + (size_t)i * 4) = o;
  }
}

// ---------------- prep: fp32 (rows x cols) -> bf16 transposed (cols x rows) ----
__global__ void transpose_cast_kernel(const float* __restrict__ in,
                                      unsigned short* __restrict__ out,
                                      int rows, int cols) {
  __shared__ float tile[32][33];
  const int t = threadIdx.x, tx = t & 31, ty = t >> 5;
  const int c0 = blockIdx.x * 32, r0 = blockIdx.y * 32;
#pragma unroll
  for (int j = 0; j < 4; j++)
    tile[ty + 8 * j][tx] = in[(size_t)(r0 + ty + 8 * j) * cols + c0 + tx];
  __syncthreads();
#pragma unroll
  for (int j = 0; j < 4; j++)
    out[(size_t)(c0 + ty + 8 * j) * rows + r0 + tx] = f2b(tile[tx][ty + 8 * j]);
}

// ---------------- GEMM: C(MxN) = A(MxK,bf16) * Bt(NxK,bf16)^T + bias ----------
// m97 structure: 128x128 tile, BK=32, 4 waves (2x2), global_load_lds width 16.
// EPI=0: scatter into Q[bh][s][d] (PRE-SCALED by QSCALE), K[bh][s][d], Vt[bh][d][s]
//        (Vt path packs 4 consecutive s into one 8B store)
// EPI=1: write fp32 C
template <int EPI>
__global__ __launch_bounds__(256, 2) void gemm_bt_kernel(
    const unsigned short* __restrict__ A, const unsigned short* __restrict__ Bt,
    const float* __restrict__ bias, float* __restrict__ Cf,
    int M, int N, int K,
    unsigned short* __restrict__ Qb, unsigned short* __restrict__ Kb,
    unsigned short* __restrict__ Vt) {
  __shared__ unsigned short lA[128 * 32];
  __shared__ unsigned short lB[128 * 32];
  const int t = threadIdx.x, lane = t & 63, w = t >> 6;
  const int l15 = lane & 15, lg = lane >> 4;
  const int wr = (w >> 1) * 64, wc = (w & 1) * 64;
  const int bm = blockIdx.x, bn = blockIdx.y;
  const char* Ag = (const char*)(A + (size_t)bm * 128 * K);
  const char* Bg = (const char*)(Bt + (size_t)bn * 128 * K);
  const int sr = t >> 2;        // staging row 0..63 (two issues: +0, +64)
  const int sc = (t & 3) * 16;  // staging col byte within 64B row
  const size_t rowb = (size_t)K * 2;

  f32x4 acc[4][4];
#pragma unroll
  for (int m = 0; m < 4; m++)
#pragma unroll
    for (int n = 0; n < 4; n++) acc[m][n] = (f32x4){0.f, 0.f, 0.f, 0.f};

  for (int k0 = 0; k0 < K; k0 += 32) {
    __syncthreads();
    const size_t kbyte = (size_t)k0 * 2;
    gld16(Ag + (size_t)sr * rowb + kbyte + sc, &lA[t * 8]);
    gld16(Ag + (size_t)(sr + 64) * rowb + kbyte + sc, &lA[2048 + t * 8]);
    gld16(Bg + (size_t)sr * rowb + kbyte + sc, &lB[t * 8]);
    gld16(Bg + (size_t)(sr + 64) * rowb + kbyte + sc, &lB[2048 + t * 8]);
    asm volatile("s_waitcnt vmcnt(0)" ::: "memory");
    __syncthreads();
    short8 af[4], bf_[4];
#pragma unroll
    for (int m = 0; m < 4; m++)
      af[m] = *(const short8*)&lA[(wr + m * 16 + l15) * 32 + lg * 8];
#pragma unroll
    for (int n = 0; n < 4; n++)
      bf_[n] = *(const short8*)&lB[(wc + n * 16 + l15) * 32 + lg * 8];
#pragma unroll
    for (int m = 0; m < 4; m++)
#pragma unroll
      for (int n = 0; n < 4; n++)
        acc[m][n] = MFMA16(af[m], bf_[n], acc[m][n]);
  }

#pragma unroll
  for (int m = 0; m < 4; m++) {
#pragma unroll
    for (int n = 0; n < 4; n++) {
      const int row0 = bm * 128 + wr + m * 16 + lg * 4;  // multiple of 4
      const int col = bn * 128 + wc + n * 16 + l15;
      const float bv = bias[col];
      if (EPI == 1) {
#pragma unroll
        for (int rr = 0; rr < 4; rr++)
          Cf[(size_t)(row0 + rr) * N + col] = acc[m][n][rr] + bv;
      } else {
        const int three = col >> 10, rem = col & 1023;
        const int h = rem >> 6, d = rem & 63;
        const int b = row0 >> 11, s0 = row0 & 2047;  // s0..s0+3 same page
        const size_t bh = (size_t)(b * NH + h);
        if (three == 0) {
#pragma unroll
          for (int rr = 0; rr < 4; rr++)
            Qb[(bh * SEQ + s0 + rr) * HD + d] = f2b((acc[m][n][rr] + bv) * QSCALE);
        } else if (three == 1) {
#pragma unroll
          for (int rr = 0; rr < 4; rr++)
            Kb[(bh * SEQ + s0 + rr) * HD + d] = f2b(acc[m][n][rr] + bv);
        } else {
          u16x4 pk;
#pragma unroll
          for (int rr = 0; rr < 4; rr++) pk[rr] = f2b(acc[m][n][rr] + bv);
          *(u16x4*)&Vt[(bh * HD + d) * SEQ + s0] = pk;  // 8B aligned store
        }
      }
    }
  }
}

// ---------------- flash attention v6: L2-direct, barrier-free ----------------
// m169 lesson: K/V per XCD (8 bh x 512KB = 4MB, via T1 remap) fits XCD-L2;
// whole K/V (32MB) fits L3. So: NO LDS staging -- MFMA fragments read straight
// from global (L2-served), NO __syncthreads in the loop, waves fully
// independent. Only LDS use: 2KB/wave P-exchange buffer (sequential per h;
// LDS pipe is in-order per wave, so no barrier needed).
__global__ __launch_bounds__(256, 4) void attn_kernel(
    const unsigned short* __restrict__ Qb, const unsigned short* __restrict__ Kb,
    const unsigned short* __restrict__ Vt, unsigned short* __restrict__ AO) {
  __shared__ unsigned short pT[4][16 * 64];  // 8KB total
  const int t = threadIdx.x, lane = t & 63, w = t >> 6;
  const int l15 = lane & 15, lg = lane >> 4;
  // T1: XCD-aware bijective remap -- all 16 q-blocks of one bh on one XCD
  const int flat = blockIdx.y * 16 + blockIdx.x;  // 0..1023
  const int xcd = flat & 7, j = flat >> 3;        // j 0..127
  const int bh = xcd * 8 + (j >> 4);
  const int q0 = (j & 15) * 128;
  const char* Qg = (const char*)(Qb + (size_t)bh * SEQ * HD);
  const char* Kg = (const char*)(Kb + (size_t)bh * SEQ * HD);
  const char* Vg = (const char*)(Vt + (size_t)bh * HD * SEQ);

  // Q fragments (B-operand), 2 q-groups x 2 k-halves, in registers all sweep
  short8 qa[2][2];
#pragma unroll
  for (int h = 0; h < 2; h++) {
    const char* qrow = Qg + (size_t)(q0 + w * 32 + h * 16 + l15) * 128;
    qa[h][0] = *(const short8*)(qrow + lg * 16);
    qa[h][1] = *(const short8*)(qrow + 64 + lg * 16);
  }

  f32x4 o[2][4];
#pragma unroll
  for (int h = 0; h < 2; h++)
#pragma unroll
    for (int n = 0; n < 4; n++) o[h][n] = (f32x4){0.f, 0.f, 0.f, 0.f};
  float m_r[2] = {-1e30f, -1e30f}, l_r[2] = {0.f, 0.f};

  for (int kv0 = 0; kv0 < SEQ; kv0 += 64) {
    // S^T = K Q^T, K fragments direct from global (L2), shared across h
    f32x4 s[2][4];
#pragma unroll
    for (int h = 0; h < 2; h++)
#pragma unroll
      for (int n = 0; n < 4; n++) s[h][n] = (f32x4){0.f, 0.f, 0.f, 0.f};
    __builtin_amdgcn_s_setprio(1);
#pragma unroll
    for (int n = 0; n < 4; n++) {
      const char* kr = Kg + (size_t)(kv0 + n * 16 + l15) * 128;
      short8 a0 = *(const short8*)(kr + lg * 16);
      short8 a1 = *(const short8*)(kr + 64 + lg * 16);
      s[0][n] = MFMA16(a0, qa[0][0], s[0][n]);
      s[0][n] = MFMA16(a1, qa[0][1], s[0][n]);
      s[1][n] = MFMA16(a0, qa[1][0], s[1][n]);
      s[1][n] = MFMA16(a1, qa[1][1], s[1][n]);
    }
    __builtin_amdgcn_s_setprio(0);

    // per-lane tile max for each q-group (this lane's q = h*16 + l15)
    float mx[2];
#pragma unroll
    for (int h = 0; h < 2; h++) {
      float m0 = fmaxf(fmaxf(s[h][0][0], s[h][0][1]), fmaxf(s[h][0][2], s[h][0][3]));
#pragma unroll
      for (int n = 1; n < 4; n++) {
        m0 = fmaxf(m0, fmaxf(fmaxf(s[h][n][0], s[h][n][1]), fmaxf(s[h][n][2], s[h][n][3])));
      }
      m0 = fmaxf(m0, __shfl_xor(m0, 16, 64));
      m0 = fmaxf(m0, __shfl_xor(m0, 32, 64));
      mx[h] = m0;
    }

    // defer-max: rescale only when some row's max grew past the threshold
    const int grow = (mx[0] > m_r[0] + LOG2_THR) | (mx[1] > m_r[1] + LOG2_THR);
    if (__any(grow)) {
      float al[2];
#pragma unroll
      for (int h = 0; h < 2; h++) {
        const float nm = fmaxf(m_r[h], mx[h]);
        al[h] = exp2v(m_r[h] - nm);
        m_r[h] = nm;
        l_r[h] *= al[h];
      }
#pragma unroll
      for (int h = 0; h < 2; h++)
#pragma unroll
        for (int r = 0; r < 4; r++) {
          const float alb = __shfl(al[h], lg * 4 + r, 64);
#pragma unroll
          for (int n = 0; n < 4; n++) o[h][n][r] *= alb;
        }
    }

    // P = exp2(s - m) (native v_exp_f32); per-wave LDS exchange, h sequential
    // (same 2KB region; per-wave LDS ops are in-order -> no barrier)
    char* pb = (char*)&pT[w][0];
    const int swp = (l15 & 7) << 4;
    short8 pa[2][2];
#pragma unroll
    for (int h = 0; h < 2; h++) {
      float rs = 0.f;
#pragma unroll
      for (int n = 0; n < 4; n++) {
#pragma unroll
        for (int r = 0; r < 4; r++) {
          const float p = exp2v(s[h][n][r] - m_r[h]);
          s[h][n][r] = p;
          rs += p;
        }
        u32x2 c;
        c.x = pk2(s[h][n][0], s[h][n][1]);
        c.y = pk2(s[h][n][2], s[h][n][3]);
        *(u32x2*)(pb + l15 * 128 + ((n * 32 + lg * 8) ^ swp)) = c;
      }
      rs += __shfl_xor(rs, 16, 64);
      rs += __shfl_xor(rs, 32, 64);
      l_r[h] += rs;
      const char* pr = pb + l15 * 128;
      pa[h][0] = *(const short8*)(pr + ((lg * 16) ^ swp));
      pa[h][1] = *(const short8*)(pr + ((64 + lg * 16) ^ swp));
    }

    // O += P V; V^T fragments direct from global (row stride SEQ*2 bytes)
    __builtin_amdgcn_s_setprio(1);
#pragma unroll
    for (int n = 0; n < 4; n++) {
      const char* vr = Vg + (size_t)(n * 16 + l15) * (SEQ * 2) + (size_t)kv0 * 2;
      short8 b0 = *(const short8*)(vr + lg * 16);
      short8 b1 = *(const short8*)(vr + 64 + lg * 16);
      o[0][n] = MFMA16(pa[0][0], b0, o[0][n]);
      o[0][n] = MFMA16(pa[0][1], b1, o[0][n]);
      o[1][n] = MFMA16(pa[1][0], b0, o[1][n]);
      o[1][n] = MFMA16(pa[1][1], b1, o[1][n]);
    }
    __builtin_amdgcn_s_setprio(0);
  }

  // epilogue: O /= l (per-lane inverse, broadcast to o-rows), write AO
  float inv[2];
#pragma unroll
  for (int h = 0; h < 2; h++) inv[h] = 1.f / l_r[h];
  const int b = bh >> 4, hh = bh & 15;
  unsigned short* aob = AO + (size_t)b * SEQ * DIM + (size_t)hh * HD;
#pragma unroll
  for (int h = 0; h < 2; h++)
#pragma unroll
    for (int r = 0; r < 4; r++) {
      const float lb = __shfl(inv[h], lg * 4 + r, 64);
      const int s_ = q0 + w * 32 + h * 16 + lg * 4 + r;
#pragma unroll
      for (int n = 0; n < 4; n++) {
        const int d_ = n * 16 + l15;
        aob[(size_t)s_ * DIM + d_] = f2b(o[h][n][r] * lb);
      }
    }
}

extern "C" void kernel_launch(void* const* d_in, const int* in_sizes, int n_in,
                              void* d_out, int out_size, void* d_ws, size_t ws_size,
                              hipStream_t stream) {
  const float* x = (const float*)d_in[0];       // (4,2048,1024)
  const float* w_qkv = (const float*)d_in[1];   // (1024,3072)
  const float* b_qkv = (const float*)d_in[2];   // (3072,)
  const float* w_out = (const float*)d_in[3];   // (1024,1024)
  const float* b_out = (const float*)d_in[4];   // (1024,)
  float* out = (float*)d_out;                   // (4,2048,1024) fp32

  char* ws = (char*)d_ws;  // needs ~88 MB
  unsigned short* xb    = (unsigned short*)(ws);                 // 16 MB: x bf16 (8192x1024)
  unsigned short* wqkvT = (unsigned short*)(ws + (16u << 20));   // 6 MB: (3072x1024)
  unsigned short* woT   = (unsigned short*)(ws + (22u << 20));   // 2 MB: (1024x1024)
  unsigned short* Qb    = (unsigned short*)(ws + (24u << 20));   // 16 MB: [bh][s][d]
  unsigned short* Kb    = (unsigned short*)(ws + (40u << 20));   // 16 MB
  unsigned short* Vt    = (unsigned short*)(ws + (56u << 20));   // 16 MB: [bh][d][s]
  unsigned short* AO    = (unsigned short*)(ws + (72u << 20));   // 16 MB: (8192x1024)

  const int M = 4 * SEQ;  // 8192

  cast_bf16_kernel<<<2048, 256, 0, stream>>>(x, xb, M * DIM / 4);
  transpose_cast_kernel<<<dim3(3 * DIM / 32, DIM / 32), 256, 0, stream>>>(w_qkv, wqkvT, DIM, 3 * DIM);
  transpose_cast_kernel<<<dim3(DIM / 32, DIM / 32), 256, 0, stream>>>(w_out, woT, DIM, DIM);

  gemm_bt_kernel<0><<<dim3(M / 128, 3 * DIM / 128), 256, 0, stream>>>(
      xb, wqkvT, b_qkv, nullptr, M, 3 * DIM, DIM, Qb, Kb, Vt);

  attn_kernel<<<dim3(SEQ / 128, 4 * NH), 256, 0, stream>>>(Qb, Kb, Vt, AO);

  gemm_bt_kernel<1><<<dim3(M / 128, DIM / 128), 256, 0, stream>>>(
      AO, woT, b_out, out, M, DIM, DIM, nullptr, nullptr, nullptr);
}

// Round 9
// 295.709 us; speedup vs baseline: 1.4205x; 1.4205x over previous
//
#include <hip/hip_runtime.h>
#include <hip/hip_bf16.h>
#include <stdint.h>

// B=4, S=2048, D=1024, H=16, Hd=64
#define SEQ 2048
#define DIM 1024
#define NH 16
#define HD 64

typedef __attribute__((ext_vector_type(8))) short short8;
typedef __attribute__((ext_vector_type(4))) float f32x4;
typedef __attribute__((ext_vector_type(4))) float float4v;
typedef __attribute__((ext_vector_type(4))) unsigned short u16x4;
typedef __attribute__((ext_vector_type(2))) unsigned int u32x2;

#define MFMA16(a, b, c) __builtin_amdgcn_mfma_f32_16x16x32_bf16(a, b, c, 0, 0, 0)

// 0.125 * log2(e): folds both the 1/sqrt(Hd) scale and the exp->exp2 base
// change into the Q projection, so attention softmax uses exp2 directly.
#define QSCALE 0.1803368801111244f
#define LOG2_THR 11.0f  // defer-max threshold (log2 domain), P <= 2^11

__device__ __forceinline__ unsigned short f2b(float f) {
  union { float f; unsigned int u; } x; x.f = f;
  unsigned int r = (x.u + 0x7FFFu + ((x.u >> 16) & 1u)) >> 16;
  return (unsigned short)r;
}

// native exp2: v_exp_f32 (ISA section 3: D = 2^S0). exp2f() is the OCML
// precise libm path (~10+ VALU each) -- that was the round-3/4 VALU bloat.
__device__ __forceinline__ float exp2v(float x) {
  float r;
  asm("v_exp_f32 %0, %1" : "=v"(r) : "v"(x));
  return r;
}

// pack two f32 -> one u32 of 2xbf16 (low = a, high = b), round-nearest
__device__ __forceinline__ unsigned int pk2(float a, float b) {
  __hip_bfloat162 h = __float22bfloat162_rn(float2{a, b});
  union { __hip_bfloat162 h; unsigned int u; } c; c.h = h;
  return c.u;
}

// global -> LDS async copy, 16B per lane. LDS dest must be linear (base + lane*16).
__device__ __forceinline__ void gld16(const void* g, void* l) {
  __builtin_amdgcn_global_load_lds(
      (const __attribute__((address_space(1))) unsigned int*)(uintptr_t)g,
      (__attribute__((address_space(3))) unsigned int*)(unsigned int)(uintptr_t)l,
      16, 0, 0);
}

// ---------------- prep: fp32 -> bf16 cast (vectorized) ----------------
__global__ void cast_bf16_kernel(const float* __restrict__ in,
                                 unsigned short* __restrict__ out, int n4) {
  int stride = gridDim.x * blockDim.x;
  for (int i = blockIdx.x * blockDim.x + threadIdx.x; i < n4; i += stride) {
    float4v v = *(const float4v*)(in + (size_t)i * 4);
    u16x4 o;
    o.x = f2b(v.x); o.y = f2b(v.y); o.z = f2b(v.z); o.w = f2b(v.w);
    *(u16x4*)(out + (size_t)i * 4) = o;
  }
}

// ---------------- prep: fp32 (rows x cols) -> bf16 transposed (cols x rows) ----
__global__ void transpose_cast_kernel(const float* __restrict__ in,
                                      unsigned short* __restrict__ out,
                                      int rows, int cols) {
  __shared__ float tile[32][33];
  const int t = threadIdx.x, tx = t & 31, ty = t >> 5;
  const int c0 = blockIdx.x * 32, r0 = blockIdx.y * 32;
#pragma unroll
  for (int j = 0; j < 4; j++)
    tile[ty + 8 * j][tx] = in[(size_t)(r0 + ty + 8 * j) * cols + c0 + tx];
  __syncthreads();
#pragma unroll
  for (int j = 0; j < 4; j++)
    out[(size_t)(c0 + ty + 8 * j) * rows + r0 + tx] = f2b(tile[tx][ty + 8 * j]);
}

// ---------------- GEMM: C(MxN) = A(MxK,bf16) * Bt(NxK,bf16)^T + bias ----------
// m97 tile (128x128, BK=32, 4 waves 2x2, gld16 width-16) upgraded to the
// T3 "minimum 2-phase" recipe: LDS double-buffer, STAGE(t+1) issued BEFORE
// compute of t, ONE vmcnt(0)+barrier per K-step (barrier proves all reads of
// the write-target buffer finished -> no race).
// EPI=0: scatter into Q[bh][s][d] (PRE-SCALED by QSCALE), K[bh][s][d], Vt[bh][d][s]
// EPI=1: write fp32 C
template <int EPI>
__global__ __launch_bounds__(256, 2) void gemm_bt_kernel(
    const unsigned short* __restrict__ A, const unsigned short* __restrict__ Bt,
    const float* __restrict__ bias, float* __restrict__ Cf,
    int M, int N, int K,
    unsigned short* __restrict__ Qb, unsigned short* __restrict__ Kb,
    unsigned short* __restrict__ Vt) {
  __shared__ unsigned short lA[2][128 * 32];
  __shared__ unsigned short lB[2][128 * 32];
  const int t = threadIdx.x, lane = t & 63, w = t >> 6;
  const int l15 = lane & 15, lg = lane >> 4;
  const int wr = (w >> 1) * 64, wc = (w & 1) * 64;
  const int bm = blockIdx.x, bn = blockIdx.y;
  const char* Ag = (const char*)(A + (size_t)bm * 128 * K);
  const char* Bg = (const char*)(Bt + (size_t)bn * 128 * K);
  const int sr = t >> 2;        // staging row 0..63 (two issues: +0, +64)
  const int sc = (t & 3) * 16;  // staging col byte within 64B row
  const size_t rowb = (size_t)K * 2;

#define GSTAGE(buf, k0_)                                                    \
  do {                                                                      \
    const size_t kb_ = (size_t)(k0_) * 2;                                   \
    gld16(Ag + (size_t)sr * rowb + kb_ + sc, &lA[buf][t * 8]);              \
    gld16(Ag + (size_t)(sr + 64) * rowb + kb_ + sc, &lA[buf][2048 + t * 8]);\
    gld16(Bg + (size_t)sr * rowb + kb_ + sc, &lB[buf][t * 8]);              \
    gld16(Bg + (size_t)(sr + 64) * rowb + kb_ + sc, &lB[buf][2048 + t * 8]);\
  } while (0)

  f32x4 acc[4][4];
#pragma unroll
  for (int m = 0; m < 4; m++)
#pragma unroll
    for (int n = 0; n < 4; n++) acc[m][n] = (f32x4){0.f, 0.f, 0.f, 0.f};

  GSTAGE(0, 0);
  asm volatile("s_waitcnt vmcnt(0)" ::: "memory");
  __syncthreads();
  int cur = 0;

  for (int k0 = 0; k0 < K; k0 += 32) {
    if (k0 + 32 < K) GSTAGE(cur ^ 1, k0 + 32);  // prefetch next K-tile
    short8 af[4], bf_[4];
#pragma unroll
    for (int m = 0; m < 4; m++)
      af[m] = *(const short8*)&lA[cur][(wr + m * 16 + l15) * 32 + lg * 8];
#pragma unroll
    for (int n = 0; n < 4; n++)
      bf_[n] = *(const short8*)&lB[cur][(wc + n * 16 + l15) * 32 + lg * 8];
    __builtin_amdgcn_s_setprio(1);
#pragma unroll
    for (int m = 0; m < 4; m++)
#pragma unroll
      for (int n = 0; n < 4; n++)
        acc[m][n] = MFMA16(af[m], bf_[n], acc[m][n]);
    __builtin_amdgcn_s_setprio(0);
    asm volatile("s_waitcnt vmcnt(0)" ::: "memory");
    __syncthreads();
    cur ^= 1;
  }
#undef GSTAGE

#pragma unroll
  for (int m = 0; m < 4; m++) {
#pragma unroll
    for (int n = 0; n < 4; n++) {
      const int row0 = bm * 128 + wr + m * 16 + lg * 4;  // multiple of 4
      const int col = bn * 128 + wc + n * 16 + l15;
      const float bv = bias[col];
      if (EPI == 1) {
#pragma unroll
        for (int rr = 0; rr < 4; rr++)
          Cf[(size_t)(row0 + rr) * N + col] = acc[m][n][rr] + bv;
      } else {
        const int three = col >> 10, rem = col & 1023;
        const int h = rem >> 6, d = rem & 63;
        const int b = row0 >> 11, s0 = row0 & 2047;  // s0..s0+3 same page
        const size_t bh = (size_t)(b * NH + h);
        if (three == 0) {
#pragma unroll
          for (int rr = 0; rr < 4; rr++)
            Qb[(bh * SEQ + s0 + rr) * HD + d] = f2b((acc[m][n][rr] + bv) * QSCALE);
        } else if (three == 1) {
#pragma unroll
          for (int rr = 0; rr < 4; rr++)
            Kb[(bh * SEQ + s0 + rr) * HD + d] = f2b(acc[m][n][rr] + bv);
        } else {
          u16x4 pk;
#pragma unroll
          for (int rr = 0; rr < 4; rr++) pk[rr] = f2b(acc[m][n][rr] + bv);
          *(u16x4*)&Vt[(bh * HD + d) * SEQ + s0] = pk;  // 8B aligned store
        }
      }
    }
  }
}

// ---------------- flash attention v5 (reverted: verified 129.6us) ----------
// r3 structure (single 64-kv tile, dbuf, 4 waves x 32 q-rows) + T1 XCD remap
// + native v_exp_f32 softmax. K tile [64][64] and V^T tile [64][64] rows
// XOR-swizzled (byte ^= (row&7)<<4) via pre-swizzled gld16 source (rule 21).
__global__ __launch_bounds__(256, 3) void attn_kernel(
    const unsigned short* __restrict__ Qb, const unsigned short* __restrict__ Kb,
    const unsigned short* __restrict__ Vt, unsigned short* __restrict__ AO) {
  __shared__ unsigned short kT[2][64 * 64];
  __shared__ unsigned short vT[2][64 * 64];
  __shared__ unsigned short pT[4][32 * 64];
  const int t = threadIdx.x, lane = t & 63, w = t >> 6;
  const int l15 = lane & 15, lg = lane >> 4;
  // T1: XCD-aware bijective remap -- all 16 q-blocks of one bh on one XCD
  const int flat = blockIdx.y * 16 + blockIdx.x;  // 0..1023
  const int xcd = flat & 7, j = flat >> 3;        // j 0..127
  const int bh = xcd * 8 + (j >> 4);
  const int q0 = (j & 15) * 128;
  const char* Qg = (const char*)(Qb + (size_t)bh * SEQ * HD);
  const char* Kg = (const char*)(Kb + (size_t)bh * SEQ * HD);
  const char* Vg = (const char*)(Vt + (size_t)bh * HD * SEQ);

  // Q fragments (B-operand), 2 q-groups x 2 k-halves, in registers all sweep
  short8 qa[2][2];
#pragma unroll
  for (int h = 0; h < 2; h++) {
    const char* qrow = Qg + (size_t)(q0 + w * 32 + h * 16 + l15) * 128;
    qa[h][0] = *(const short8*)(qrow + lg * 16);
    qa[h][1] = *(const short8*)(qrow + 64 + lg * 16);
  }

  f32x4 o[2][4];
#pragma unroll
  for (int h = 0; h < 2; h++)
#pragma unroll
    for (int n = 0; n < 4; n++) o[h][n] = (f32x4){0.f, 0.f, 0.f, 0.f};
  float m_r[2] = {-1e30f, -1e30f}, l_r[2] = {0.f, 0.f};

  const int sr0 = t >> 3;        // staging row 0..31 (second issue +32)
  const int scx = (t & 7) * 16;  // staging col byte within 128B row

#define STAGE(buf, kv0_)                                                               \
  do {                                                                                 \
    const int r0_ = sr0, r1_ = sr0 + 32;                                               \
    gld16(Kg + (size_t)((kv0_) + r0_) * 128 + (scx ^ ((r0_ & 7) << 4)),                \
          &kT[buf][t * 8]);                                                            \
    gld16(Kg + (size_t)((kv0_) + r1_) * 128 + (scx ^ ((r1_ & 7) << 4)),                \
          &kT[buf][2048 + t * 8]);                                                     \
    gld16(Vg + (size_t)r0_ * (SEQ * 2) + (size_t)(kv0_) * 2 + (scx ^ ((r0_ & 7) << 4)),\
          &vT[buf][t * 8]);                                                            \
    gld16(Vg + (size_t)r1_ * (SEQ * 2) + (size_t)(kv0_) * 2 + (scx ^ ((r1_ & 7) << 4)),\
          &vT[buf][2048 + t * 8]);                                                     \
  } while (0)

  STAGE(0, 0);
  asm volatile("s_waitcnt vmcnt(0)" ::: "memory");
  __syncthreads();
  int cur = 0;

  for (int kv0 = 0; kv0 < SEQ; kv0 += 64) {
    if (kv0 + 64 < SEQ) STAGE(cur ^ 1, kv0 + 64);  // prefetch next tile

    // S^T = K Q^T for both q-groups; K fragments shared across h.
    const char* kb = (const char*)&kT[cur][0];
    f32x4 s[2][4];
#pragma unroll
    for (int h = 0; h < 2; h++)
#pragma unroll
      for (int n = 0; n < 4; n++) s[h][n] = (f32x4){0.f, 0.f, 0.f, 0.f};
    __builtin_amdgcn_s_setprio(1);
#pragma unroll
    for (int n = 0; n < 4; n++) {
      const int row = n * 16 + l15;
      const char* kr = kb + row * 128;
      const int sw = (row & 7) << 4;
      short8 a0 = *(const short8*)(kr + ((lg * 16) ^ sw));
      short8 a1 = *(const short8*)(kr + ((64 + lg * 16) ^ sw));
      s[0][n] = MFMA16(a0, qa[0][0], s[0][n]);
      s[0][n] = MFMA16(a1, qa[0][1], s[0][n]);
      s[1][n] = MFMA16(a0, qa[1][0], s[1][n]);
      s[1][n] = MFMA16(a1, qa[1][1], s[1][n]);
    }
    __builtin_amdgcn_s_setprio(0);

    // per-lane tile max for each q-group (this lane's q = h*16 + l15)
    float mx[2];
#pragma unroll
    for (int h = 0; h < 2; h++) {
      float m0 = fmaxf(fmaxf(s[h][0][0], s[h][0][1]), fmaxf(s[h][0][2], s[h][0][3]));
#pragma unroll
      for (int n = 1; n < 4; n++) {
        m0 = fmaxf(m0, fmaxf(fmaxf(s[h][n][0], s[h][n][1]), fmaxf(s[h][n][2], s[h][n][3])));
      }
      m0 = fmaxf(m0, __shfl_xor(m0, 16, 64));
      m0 = fmaxf(m0, __shfl_xor(m0, 32, 64));
      mx[h] = m0;
    }

    // defer-max: rescale only when some row's max grew past the threshold
    const int grow = (mx[0] > m_r[0] + LOG2_THR) | (mx[1] > m_r[1] + LOG2_THR);
    if (__any(grow)) {
      float al[2];
#pragma unroll
      for (int h = 0; h < 2; h++) {
        const float nm = fmaxf(m_r[h], mx[h]);
        al[h] = exp2v(m_r[h] - nm);
        m_r[h] = nm;
        l_r[h] *= al[h];
      }
#pragma unroll
      for (int h = 0; h < 2; h++)
#pragma unroll
        for (int r = 0; r < 4; r++) {
          const float alb = __shfl(al[h], lg * 4 + r, 64);
#pragma unroll
          for (int n = 0; n < 4; n++) o[h][n][r] *= alb;
        }
    }

    // P = exp2(s - m) via native v_exp_f32, row sums, pack to per-wave LDS
    char* pb = (char*)&pT[w][0];
    const int swp = (l15 & 7) << 4;
#pragma unroll
    for (int h = 0; h < 2; h++) {
      float rs = 0.f;
#pragma unroll
      for (int n = 0; n < 4; n++) {
#pragma unroll
        for (int r = 0; r < 4; r++) {
          const float p = exp2v(s[h][n][r] - m_r[h]);
          s[h][n][r] = p;
          rs += p;
        }
        u32x2 c;
        c.x = pk2(s[h][n][0], s[h][n][1]);
        c.y = pk2(s[h][n][2], s[h][n][3]);
        *(u32x2*)(pb + (h * 16 + l15) * 128 + ((n * 32 + lg * 8) ^ swp)) = c;
      }
      rs += __shfl_xor(rs, 16, 64);
      rs += __shfl_xor(rs, 32, 64);
      l_r[h] += rs;
    }
    short8 pa[2][2];
#pragma unroll
    for (int h = 0; h < 2; h++) {
      const char* pr = pb + (h * 16 + l15) * 128;
      pa[h][0] = *(const short8*)(pr + ((lg * 16) ^ swp));
      pa[h][1] = *(const short8*)(pr + ((64 + lg * 16) ^ swp));
    }

    // O += P V (B^T = Vt[d][kv]); V fragments shared across h.
    const char* vb = (const char*)&vT[cur][0];
    __builtin_amdgcn_s_setprio(1);
#pragma unroll
    for (int n = 0; n < 4; n++) {
      const int row = n * 16 + l15;
      const char* vr = vb + row * 128;
      const int sw = (row & 7) << 4;
      short8 b0 = *(const short8*)(vr + ((lg * 16) ^ sw));
      short8 b1 = *(const short8*)(vr + ((64 + lg * 16) ^ sw));
      o[0][n] = MFMA16(pa[0][0], b0, o[0][n]);
      o[0][n] = MFMA16(pa[0][1], b1, o[0][n]);
      o[1][n] = MFMA16(pa[1][0], b0, o[1][n]);
      o[1][n] = MFMA16(pa[1][1], b1, o[1][n]);
    }
    __builtin_amdgcn_s_setprio(0);

    asm volatile("s_waitcnt vmcnt(0)" ::: "memory");
    __syncthreads();
    cur ^= 1;
  }
#undef STAGE

  // epilogue: O /= l (per-lane inverse, broadcast to o-rows), write AO
  float inv[2];
#pragma unroll
  for (int h = 0; h < 2; h++) inv[h] = 1.f / l_r[h];
  const int b = bh >> 4, hh = bh & 15;
  unsigned short* aob = AO + (size_t)b * SEQ * DIM + (size_t)hh * HD;
#pragma unroll
  for (int h = 0; h < 2; h++)
#pragma unroll
    for (int r = 0; r < 4; r++) {
      const float lb = __shfl(inv[h], lg * 4 + r, 64);
      const int s_ = q0 + w * 32 + h * 16 + lg * 4 + r;
#pragma unroll
      for (int n = 0; n < 4; n++) {
        const int d_ = n * 16 + l15;
        aob[(size_t)s_ * DIM + d_] = f2b(o[h][n][r] * lb);
      }
    }
}

extern "C" void kernel_launch(void* const* d_in, const int* in_sizes, int n_in,
                              void* d_out, int out_size, void* d_ws, size_t ws_size,
                              hipStream_t stream) {
  const float* x = (const float*)d_in[0];       // (4,2048,1024)
  const float* w_qkv = (const float*)d_in[1];   // (1024,3072)
  const float* b_qkv = (const float*)d_in[2];   // (3072,)
  const float* w_out = (const float*)d_in[3];   // (1024,1024)
  const float* b_out = (const float*)d_in[4];   // (1024,)
  float* out = (float*)d_out;                   // (4,2048,1024) fp32

  char* ws = (char*)d_ws;  // needs ~88 MB
  unsigned short* xb    = (unsigned short*)(ws);                 // 16 MB: x bf16 (8192x1024)
  unsigned short* wqkvT = (unsigned short*)(ws + (16u << 20));   // 6 MB: (3072x1024)
  unsigned short* woT   = (unsigned short*)(ws + (22u << 20));   // 2 MB: (1024x1024)
  unsigned short* Qb    = (unsigned short*)(ws + (24u << 20));   // 16 MB: [bh][s][d]
  unsigned short* Kb    = (unsigned short*)(ws + (40u << 20));   // 16 MB
  unsigned short* Vt    = (unsigned short*)(ws + (56u << 20));   // 16 MB: [bh][d][s]
  unsigned short* AO    = (unsigned short*)(ws + (72u << 20));   // 16 MB: (8192x1024)

  const int M = 4 * SEQ;  // 8192

  cast_bf16_kernel<<<2048, 256, 0, stream>>>(x, xb, M * DIM / 4);
  transpose_cast_kernel<<<dim3(3 * DIM / 32, DIM / 32), 256, 0, stream>>>(w_qkv, wqkvT, DIM, 3 * DIM);
  transpose_cast_kernel<<<dim3(DIM / 32, DIM / 32), 256, 0, stream>>>(w_out, woT, DIM, DIM);

  gemm_bt_kernel<0><<<dim3(M / 128, 3 * DIM / 128), 256, 0, stream>>>(
      xb, wqkvT, b_qkv, nullptr, M, 3 * DIM, DIM, Qb, Kb, Vt);

  attn_kernel<<<dim3(SEQ / 128, 4 * NH), 256, 0, stream>>>(Qb, Kb, Vt, AO);

  gemm_bt_kernel<1><<<dim3(M / 128, DIM / 128), 256, 0, stream>>>(
      AO, woT, b_out, out, M, DIM, DIM, nullptr, nullptr, nullptr);
}